// Round 1
// baseline (271.096 us; speedup 1.0000x reference)
//
#include <hip/hip_runtime.h>

// Problem constants (B,H,T,D = 4,16,4096,64; N_TASKS=8, K_LEN=128)
#define B_   4
#define H_   16
#define T_   4096
#define D_   64
#define KL_  128
#define NT_  8
#define NTOK (B_ * T_)      // 16384 tokens
#define CAP  4096           // fixed bucket capacity (avg 2048, binomial max ~2300)

typedef __bf16 bf16;
typedef __attribute__((ext_vector_type(8))) __bf16 bf16x8;
typedef __attribute__((ext_vector_type(4))) __bf16 bf16x4;
typedef __attribute__((ext_vector_type(4))) float  floatx4;
typedef __attribute__((ext_vector_type(4))) unsigned int uint4v;

// ws layout (ints): [0..7] per-task counts; [8 ..] buckets, CAP per task.
__global__ void zero_counts_k(int* __restrict__ ws) {
    if (threadIdx.x < NT_) ws[threadIdx.x] = 0;
}

// One thread per token; wave-aggregated atomics (8 atomics/wave, not 64).
__global__ void scatter_tokens_k(const int* __restrict__ trk, int* __restrict__ ws) {
    int* counts = ws;
    int* bucket = ws + NT_;
    int idx  = blockIdx.x * blockDim.x + threadIdx.x;
    int lane = threadIdx.x & 63;
    int task = (idx < NTOK) ? trk[idx] : -1;
    unsigned long long mymask = 0ull;
    int myCnt = 0;
#pragma unroll
    for (int i = 0; i < NT_; i++) {
        unsigned long long m = __ballot(task == i);
        if (task == i) mymask = m;
        if (lane == i) myCnt = (int)__popcll(m);
    }
    int b0 = 0;
    if (lane < NT_) b0 = atomicAdd(&counts[lane], myCnt);
    int myBase = __shfl(b0, (task < 0) ? 0 : task);
    if (idx < NTOK) {
        int pos = myBase + (int)__popcll(mymask & ((1ull << lane) - 1ull));
        bucket[task * CAP + pos] = idx;   // token id = b*T + t
    }
}

static __device__ __forceinline__ unsigned pk_bf16(float a, float b) {
    unsigned short ua = __builtin_bit_cast(unsigned short, (bf16)a);
    unsigned short ub = __builtin_bit_cast(unsigned short, (bf16)b);
    return (unsigned)ua | ((unsigned)ub << 16);
}

// Swapped-S flash attention per (task, head, chunk).
// LDS: K [128][64] bf16 XOR-swizzled (16 KB) + V^T [64][128] bf16 XOR-swizzled (16 KB) = 32 KB
// -> 4 blocks/CU (16 waves/CU) with __launch_bounds__(256,4).
// S^T = mfma(K, Q): lane (c=lane&15, quad=lane>>4) holds, for token c, keys nt*16+quad*4+r.
// Softmax is lane-local + 2 shfl_xor. P->A-layout via in-register cross-quad shuffles (no LDS).
__global__ __launch_bounds__(256, 4) void attn_k(
    const float* __restrict__ q,   const float* __restrict__ kvk,
    const float* __restrict__ kvv, const float* __restrict__ gates,
    const float* __restrict__ x,   float* __restrict__ out,
    const int* __restrict__ ws)
{
    __shared__ bf16 Kl[KL_ * D_];   // [k][d], 16B-unit swizzle: u ^= (k&7)
    __shared__ bf16 Vt[D_ * KL_];   // [d][k], 16B-unit swizzle: u ^= (d&7)

    const int task = blockIdx.z, h = blockIdx.y, chunk = blockIdx.x;
    const int cnt = ws[task];
    if (cnt == 0) return;
    const int* bucket = ws + NT_ + task * CAP;
    const float gate = gates[task];

    // ---- stage K and V^T (bf16, swizzled, no pad) ----
    {
        const size_t kvbase = (size_t)(task * H_ + h) * (KL_ * D_ / 4);
        const float4* kf = (const float4*)kvk + kvbase;
        const float4* vf = (const float4*)kvv + kvbase;
#pragma unroll
        for (int it = 0; it < 8; it++) {
            int ii = it * 256 + threadIdx.x;
            int k = ii >> 4, d4 = ii & 15;
            float4 a = kf[ii];
            bf16x4 w; w[0]=(bf16)a.x; w[1]=(bf16)a.y; w[2]=(bf16)a.z; w[3]=(bf16)a.w;
            // row k (64 elems = 8 units of 8 bf16); unit = d4>>1, half = d4&1
            *(bf16x4*)&Kl[(k << 6) + (((d4 >> 1) ^ (k & 7)) << 3) + ((d4 & 1) << 2)] = w;
            float4 v = vf[ii];
            int d0 = d4 << 2, ku = k >> 3, kl = k & 7;
            Vt[(d0+0)*128 + ((ku ^ ((d0+0)&7))<<3) + kl] = (bf16)v.x;
            Vt[(d0+1)*128 + ((ku ^ ((d0+1)&7))<<3) + kl] = (bf16)v.y;
            Vt[(d0+2)*128 + ((ku ^ ((d0+2)&7))<<3) + kl] = (bf16)v.z;
            Vt[(d0+3)*128 + ((ku ^ ((d0+3)&7))<<3) + kl] = (bf16)v.w;
        }
    }
    __syncthreads();

    const int lane = threadIdx.x & 63;
    const int wave = threadIdx.x >> 6;
    const int c = lane & 15, quad = lane >> 4;
    const int cswz = c & 7;
    // P-routing source lanes: dword half hsel pulls pk[..][t] from lane c+16*((2q+h)&3)
    const int src_h0 = c + 16 * (( 2 * quad     ) & 3);
    const int src_h1 = c + 16 * (( 2 * quad + 1 ) & 3);
    const bool hiSel = ((quad >> 1) & 1) != 0;   // pick pk[2kc+1] vs pk[2kc]

    for (int ts = chunk * 4 + wave; ts * 16 < cnt; ts += 32) {
        const int slotc = ts * 16 + c;
        const int tokc  = bucket[slotc < cnt ? slotc : cnt - 1];

        // ---- Q fragment (B-operand: n = token c, k-dim = quad*8+j) ----
        bf16x8 aq[2];
        {
            int bb = tokc >> 12, tt = tokc & (T_ - 1);
            const float4* qf = (const float4*)q + ((size_t)((bb * H_ + h) * T_ + tt) * (D_ / 4));
#pragma unroll
            for (int dc = 0; dc < 2; dc++) {
                float4 f0 = qf[dc * 8 + quad * 2];
                float4 f1 = qf[dc * 8 + quad * 2 + 1];
                aq[dc][0]=(bf16)f0.x; aq[dc][1]=(bf16)f0.y; aq[dc][2]=(bf16)f0.z; aq[dc][3]=(bf16)f0.w;
                aq[dc][4]=(bf16)f1.x; aq[dc][5]=(bf16)f1.y; aq[dc][6]=(bf16)f1.z; aq[dc][7]=(bf16)f1.w;
            }
        }

        // ---- x prefetch (issued AFTER Q loads so the Q vmcnt wait keeps these in flight;
        //      latency hides under QK + softmax + PV) ----
        float xr[4][4];
        int base_r[4];
#pragma unroll
        for (int r = 0; r < 4; r++) {
            int tok = __shfl(tokc, quad * 4 + r);
            int b2 = tok >> 12, t2 = tok & (T_ - 1);
            base_r[r] = ((b2 * H_ + h) * T_ + t2) * D_;
            if (ts * 16 + quad * 4 + r < cnt) {
#pragma unroll
                for (int dt = 0; dt < 4; dt++) xr[r][dt] = x[base_r[r] + dt * 16 + c];
            }
        }

        // ---- S^T = K Q^T : 8 key-tiles x 2 d-chunks (operand-swapped MFMA) ----
        floatx4 sc[8];
#pragma unroll
        for (int nt = 0; nt < 8; nt++) { floatx4 z = {0.f,0.f,0.f,0.f}; sc[nt] = z; }
        __builtin_amdgcn_s_setprio(1);
#pragma unroll
        for (int dc = 0; dc < 2; dc++) {
#pragma unroll
            for (int nt = 0; nt < 8; nt++) {
                bf16x8 ak = *(const bf16x8*)&Kl[((nt * 16 + c) << 6) + (((4 * dc + quad) ^ cswz) << 3)];
                sc[nt] = __builtin_amdgcn_mfma_f32_16x16x32_bf16(ak, aq[dc], sc[nt], 0, 0, 0);
            }
        }
        __builtin_amdgcn_s_setprio(0);

        // ---- softmax: lane-local over 32 vals + reduce across quads (2 shuffles) ----
        float m = -1e30f;
#pragma unroll
        for (int nt = 0; nt < 8; nt++)
#pragma unroll
            for (int r = 0; r < 4; r++) m = fmaxf(m, sc[nt][r]);
        m = fmaxf(m, __shfl_xor(m, 16));
        m = fmaxf(m, __shfl_xor(m, 32));
        float sum = 0.f;
#pragma unroll
        for (int nt = 0; nt < 8; nt++)
#pragma unroll
            for (int r = 0; r < 4; r++) {
                // scale 1/sqrt(64)=0.125 folded into exp2: 0.125*log2(e)
                float p = exp2f((sc[nt][r] - m) * 0.18033688011112042f);
                sc[nt][r] = p;
                sum += p;
            }
        sum += __shfl_xor(sum, 16);
        sum += __shfl_xor(sum, 32);
        float ginv = gate / sum;

        // ---- pack P to bf16 pairs: pkv[nt][t] = (P[16nt+4q+2t], P[16nt+4q+2t+1]) ----
        unsigned pkv[8][2];
#pragma unroll
        for (int nt = 0; nt < 8; nt++) {
            pkv[nt][0] = pk_bf16(sc[nt][0], sc[nt][1]);
            pkv[nt][1] = pk_bf16(sc[nt][2], sc[nt][3]);
        }

        // ---- O = P V : in-register P routing (keys kc*32+quad*8+j per lane) + 16 MFMA ----
        floatx4 acc[4];
#pragma unroll
        for (int dt = 0; dt < 4; dt++) { floatx4 z = {0.f,0.f,0.f,0.f}; acc[dt] = z; }
#pragma unroll
        for (int kc = 0; kc < 4; kc++) {
            unsigned e0 = pkv[2*kc][0],   e1 = pkv[2*kc][1];
            unsigned o0 = pkv[2*kc+1][0], o1 = pkv[2*kc+1][1];
            unsigned a0e = __shfl(e0, src_h0), a0o = __shfl(o0, src_h0);
            unsigned a1e = __shfl(e1, src_h0), a1o = __shfl(o1, src_h0);
            unsigned a2e = __shfl(e0, src_h1), a2o = __shfl(o0, src_h1);
            unsigned a3e = __shfl(e1, src_h1), a3o = __shfl(o1, src_h1);
            uint4v uw;
            uw[0] = hiSel ? a0o : a0e;
            uw[1] = hiSel ? a1o : a1e;
            uw[2] = hiSel ? a2o : a2e;
            uw[3] = hiSel ? a3o : a3e;
            bf16x8 ap = __builtin_bit_cast(bf16x8, uw);
            __builtin_amdgcn_s_setprio(1);
#pragma unroll
            for (int dt = 0; dt < 4; dt++) {
                bf16x8 bv = *(const bf16x8*)&Vt[((dt * 16 + c) << 7) + (((4 * kc + quad) ^ cswz) << 3)];
                acc[dt] = __builtin_amdgcn_mfma_f32_16x16x32_bf16(ap, bv, acc[dt], 0, 0, 0);
            }
            __builtin_amdgcn_s_setprio(0);
        }

        // ---- epilogue: normalize, gate, residual add, store ----
#pragma unroll
        for (int r = 0; r < 4; r++) {
            int slot = ts * 16 + quad * 4 + r;
            float scale = __shfl(ginv, quad * 4 + r);
            if (slot < cnt) {
#pragma unroll
                for (int dt = 0; dt < 4; dt++) {
                    int off = base_r[r] + dt * 16 + c;
                    out[off] = xr[r][dt] + acc[dt][r] * scale;
                }
            }
        }
    }
}

extern "C" void kernel_launch(void* const* d_in, const int* in_sizes, int n_in,
                              void* d_out, int out_size, void* d_ws, size_t ws_size,
                              hipStream_t stream) {
    const float* x     = (const float*)d_in[0];
    const float* q     = (const float*)d_in[1];
    const float* kvk   = (const float*)d_in[2];
    const float* kvv   = (const float*)d_in[3];
    const float* gates = (const float*)d_in[4];
    const int*   trk   = (const int*)d_in[5];
    float* out = (float*)d_out;
    int* ws = (int*)d_ws;

    zero_counts_k<<<1, 64, 0, stream>>>(ws);
    scatter_tokens_k<<<NTOK / 256, 256, 0, stream>>>(trk, ws);
    attn_k<<<dim3(8, H_, NT_), 256, 0, stream>>>(q, kvk, kvv, gates, x, out, ws);
}

// Round 2
// 270.508 us; speedup vs baseline: 1.0022x; 1.0022x over previous
//
#include <hip/hip_runtime.h>

// Problem constants (B,H,T,D = 4,16,4096,64; N_TASKS=8, K_LEN=128)
#define B_   4
#define H_   16
#define T_   4096
#define D_   64
#define KL_  128
#define NT_  8
#define NTOK (B_ * T_)      // 16384 tokens
#define CAP  4096           // fixed bucket capacity (avg 2048, binomial max ~2300)

typedef __bf16 bf16;
typedef __attribute__((ext_vector_type(8))) __bf16 bf16x8;
typedef __attribute__((ext_vector_type(4))) __bf16 bf16x4;
typedef __attribute__((ext_vector_type(4))) float  floatx4;
typedef __attribute__((ext_vector_type(4))) unsigned int uint4v;

// ws layout (ints): [0..7] per-task counts; [8 ..] buckets, CAP per task.
__global__ void zero_counts_k(int* __restrict__ ws) {
    if (threadIdx.x < NT_) ws[threadIdx.x] = 0;
}

// One thread per token; wave-aggregated atomics (8 atomics/wave, not 64).
__global__ void scatter_tokens_k(const int* __restrict__ trk, int* __restrict__ ws) {
    int* counts = ws;
    int* bucket = ws + NT_;
    int idx  = blockIdx.x * blockDim.x + threadIdx.x;
    int lane = threadIdx.x & 63;
    int task = (idx < NTOK) ? trk[idx] : -1;
    unsigned long long mymask = 0ull;
    int myCnt = 0;
#pragma unroll
    for (int i = 0; i < NT_; i++) {
        unsigned long long m = __ballot(task == i);
        if (task == i) mymask = m;
        if (lane == i) myCnt = (int)__popcll(m);
    }
    int b0 = 0;
    if (lane < NT_) b0 = atomicAdd(&counts[lane], myCnt);
    int myBase = __shfl(b0, (task < 0) ? 0 : task);
    if (idx < NTOK) {
        int pos = myBase + (int)__popcll(mymask & ((1ull << lane) - 1ull));
        bucket[task * CAP + pos] = idx;   // token id = b*T + t
    }
}

static __device__ __forceinline__ unsigned pk_bf16(float a, float b) {
    unsigned short ua = __builtin_bit_cast(unsigned short, (bf16)a);
    unsigned short ub = __builtin_bit_cast(unsigned short, (bf16)b);
    return (unsigned)ua | ((unsigned)ub << 16);
}

// Swapped-S flash attention per (task, head, chunk).
// LDS: K [128][64] bf16 XOR-swizzled (16 KB) + V^T [64][128] bf16 XOR-swizzled (16 KB) = 32 KB
// -> 4 blocks/CU (16 waves/CU).
// REGISTER BUDGET: waves_per_eu(4,4) pins the VGPR budget at 128. Round-1 lesson:
// __launch_bounds__(256,4) (min-only) let LLVM chase 8 waves/EU = 64 VGPRs and spill
// sc[8] to scratch every tile-iter (+260 MB HBM traffic, attn_k 115->150 us).
// S^T = mfma(K, Q): lane (c=lane&15, quad=lane>>4) holds, for token c, keys nt*16+quad*4+r.
// Softmax is lane-local + 2 shfl_xor. P->A-layout via in-register cross-quad shuffles (no LDS).
__global__ __launch_bounds__(256)
__attribute__((amdgpu_waves_per_eu(4, 4)))
void attn_k(
    const float* __restrict__ q,   const float* __restrict__ kvk,
    const float* __restrict__ kvv, const float* __restrict__ gates,
    const float* __restrict__ x,   float* __restrict__ out,
    const int* __restrict__ ws)
{
    __shared__ bf16 Kl[KL_ * D_];   // [k][d], 16B-unit swizzle: u ^= (k&7)
    __shared__ bf16 Vt[D_ * KL_];   // [d][k], 16B-unit swizzle: u ^= (d&7)

    const int task = blockIdx.z, h = blockIdx.y, chunk = blockIdx.x;
    const int cnt = ws[task];
    if (cnt == 0) return;
    const int* bucket = ws + NT_ + task * CAP;
    const float gate = gates[task];

    // ---- stage K and V^T (bf16, swizzled, no pad) ----
    {
        const size_t kvbase = (size_t)(task * H_ + h) * (KL_ * D_ / 4);
        const float4* kf = (const float4*)kvk + kvbase;
        const float4* vf = (const float4*)kvv + kvbase;
#pragma unroll
        for (int it = 0; it < 8; it++) {
            int ii = it * 256 + threadIdx.x;
            int k = ii >> 4, d4 = ii & 15;
            float4 a = kf[ii];
            bf16x4 w; w[0]=(bf16)a.x; w[1]=(bf16)a.y; w[2]=(bf16)a.z; w[3]=(bf16)a.w;
            // row k (64 elems = 8 units of 8 bf16); unit = d4>>1, half = d4&1
            *(bf16x4*)&Kl[(k << 6) + (((d4 >> 1) ^ (k & 7)) << 3) + ((d4 & 1) << 2)] = w;
            float4 v = vf[ii];
            int d0 = d4 << 2, ku = k >> 3, kl = k & 7;
            Vt[(d0+0)*128 + ((ku ^ ((d0+0)&7))<<3) + kl] = (bf16)v.x;
            Vt[(d0+1)*128 + ((ku ^ ((d0+1)&7))<<3) + kl] = (bf16)v.y;
            Vt[(d0+2)*128 + ((ku ^ ((d0+2)&7))<<3) + kl] = (bf16)v.z;
            Vt[(d0+3)*128 + ((ku ^ ((d0+3)&7))<<3) + kl] = (bf16)v.w;
        }
    }
    __syncthreads();

    const int lane = threadIdx.x & 63;
    const int wave = threadIdx.x >> 6;
    const int c = lane & 15, quad = lane >> 4;
    const int cswz = c & 7;
    // P-routing source lanes: dword half hsel pulls pk[..][t] from lane c+16*((2q+h)&3)
    const int src_h0 = c + 16 * (( 2 * quad     ) & 3);
    const int src_h1 = c + 16 * (( 2 * quad + 1 ) & 3);
    const bool hiSel = ((quad >> 1) & 1) != 0;   // pick pk[2kc+1] vs pk[2kc]

    for (int ts = chunk * 4 + wave; ts * 16 < cnt; ts += 32) {
        const int slotc = ts * 16 + c;
        const int tokc  = bucket[slotc < cnt ? slotc : cnt - 1];

        // ---- Q fragment (B-operand: n = token c, k-dim = quad*8+j) ----
        bf16x8 aq[2];
        {
            int bb = tokc >> 12, tt = tokc & (T_ - 1);
            const float4* qf = (const float4*)q + ((size_t)((bb * H_ + h) * T_ + tt) * (D_ / 4));
#pragma unroll
            for (int dc = 0; dc < 2; dc++) {
                float4 f0 = qf[dc * 8 + quad * 2];
                float4 f1 = qf[dc * 8 + quad * 2 + 1];
                aq[dc][0]=(bf16)f0.x; aq[dc][1]=(bf16)f0.y; aq[dc][2]=(bf16)f0.z; aq[dc][3]=(bf16)f0.w;
                aq[dc][4]=(bf16)f1.x; aq[dc][5]=(bf16)f1.y; aq[dc][6]=(bf16)f1.z; aq[dc][7]=(bf16)f1.w;
            }
        }

        // ---- x prefetch (issued AFTER Q loads so the Q vmcnt wait keeps these in flight;
        //      latency hides under QK + softmax + PV) ----
        float xr[4][4];
        int base_r[4];
#pragma unroll
        for (int r = 0; r < 4; r++) {
            int tok = __shfl(tokc, quad * 4 + r);
            int b2 = tok >> 12, t2 = tok & (T_ - 1);
            base_r[r] = ((b2 * H_ + h) * T_ + t2) * D_;
            if (ts * 16 + quad * 4 + r < cnt) {
#pragma unroll
                for (int dt = 0; dt < 4; dt++) xr[r][dt] = x[base_r[r] + dt * 16 + c];
            }
        }

        // ---- S^T = K Q^T : 8 key-tiles x 2 d-chunks (operand-swapped MFMA) ----
        floatx4 sc[8];
#pragma unroll
        for (int nt = 0; nt < 8; nt++) { floatx4 z = {0.f,0.f,0.f,0.f}; sc[nt] = z; }
        __builtin_amdgcn_s_setprio(1);
#pragma unroll
        for (int dc = 0; dc < 2; dc++) {
#pragma unroll
            for (int nt = 0; nt < 8; nt++) {
                bf16x8 ak = *(const bf16x8*)&Kl[((nt * 16 + c) << 6) + (((4 * dc + quad) ^ cswz) << 3)];
                sc[nt] = __builtin_amdgcn_mfma_f32_16x16x32_bf16(ak, aq[dc], sc[nt], 0, 0, 0);
            }
        }
        __builtin_amdgcn_s_setprio(0);

        // ---- softmax: lane-local over 32 vals + reduce across quads (2 shuffles) ----
        float m = -1e30f;
#pragma unroll
        for (int nt = 0; nt < 8; nt++)
#pragma unroll
            for (int r = 0; r < 4; r++) m = fmaxf(m, sc[nt][r]);
        m = fmaxf(m, __shfl_xor(m, 16));
        m = fmaxf(m, __shfl_xor(m, 32));
        float sum = 0.f;
#pragma unroll
        for (int nt = 0; nt < 8; nt++)
#pragma unroll
            for (int r = 0; r < 4; r++) {
                // scale 1/sqrt(64)=0.125 folded into exp2: 0.125*log2(e)
                float p = exp2f((sc[nt][r] - m) * 0.18033688011112042f);
                sc[nt][r] = p;
                sum += p;
            }
        sum += __shfl_xor(sum, 16);
        sum += __shfl_xor(sum, 32);
        float ginv = gate / sum;

        // ---- pack P to bf16 pairs: pkv[nt][t] = (P[16nt+4q+2t], P[16nt+4q+2t+1]) ----
        unsigned pkv[8][2];
#pragma unroll
        for (int nt = 0; nt < 8; nt++) {
            pkv[nt][0] = pk_bf16(sc[nt][0], sc[nt][1]);
            pkv[nt][1] = pk_bf16(sc[nt][2], sc[nt][3]);
        }

        // ---- O = P V : in-register P routing (keys kc*32+quad*8+j per lane) + 16 MFMA ----
        floatx4 acc[4];
#pragma unroll
        for (int dt = 0; dt < 4; dt++) { floatx4 z = {0.f,0.f,0.f,0.f}; acc[dt] = z; }
#pragma unroll
        for (int kc = 0; kc < 4; kc++) {
            unsigned e0 = pkv[2*kc][0],   e1 = pkv[2*kc][1];
            unsigned o0 = pkv[2*kc+1][0], o1 = pkv[2*kc+1][1];
            unsigned a0e = __shfl(e0, src_h0), a0o = __shfl(o0, src_h0);
            unsigned a1e = __shfl(e1, src_h0), a1o = __shfl(o1, src_h0);
            unsigned a2e = __shfl(e0, src_h1), a2o = __shfl(o0, src_h1);
            unsigned a3e = __shfl(e1, src_h1), a3o = __shfl(o1, src_h1);
            uint4v uw;
            uw[0] = hiSel ? a0o : a0e;
            uw[1] = hiSel ? a1o : a1e;
            uw[2] = hiSel ? a2o : a2e;
            uw[3] = hiSel ? a3o : a3e;
            bf16x8 ap = __builtin_bit_cast(bf16x8, uw);
            __builtin_amdgcn_s_setprio(1);
#pragma unroll
            for (int dt = 0; dt < 4; dt++) {
                bf16x8 bv = *(const bf16x8*)&Vt[((dt * 16 + c) << 7) + (((4 * kc + quad) ^ cswz) << 3)];
                acc[dt] = __builtin_amdgcn_mfma_f32_16x16x32_bf16(ap, bv, acc[dt], 0, 0, 0);
            }
            __builtin_amdgcn_s_setprio(0);
        }

        // ---- epilogue: normalize, gate, residual add, store ----
#pragma unroll
        for (int r = 0; r < 4; r++) {
            int slot = ts * 16 + quad * 4 + r;
            float scale = __shfl(ginv, quad * 4 + r);
            if (slot < cnt) {
#pragma unroll
                for (int dt = 0; dt < 4; dt++) {
                    int off = base_r[r] + dt * 16 + c;
                    out[off] = xr[r][dt] + acc[dt][r] * scale;
                }
            }
        }
    }
}

extern "C" void kernel_launch(void* const* d_in, const int* in_sizes, int n_in,
                              void* d_out, int out_size, void* d_ws, size_t ws_size,
                              hipStream_t stream) {
    const float* x     = (const float*)d_in[0];
    const float* q     = (const float*)d_in[1];
    const float* kvk   = (const float*)d_in[2];
    const float* kvv   = (const float*)d_in[3];
    const float* gates = (const float*)d_in[4];
    const int*   trk   = (const int*)d_in[5];
    float* out = (float*)d_out;
    int* ws = (int*)d_ws;

    zero_counts_k<<<1, 64, 0, stream>>>(ws);
    scatter_tokens_k<<<NTOK / 256, 256, 0, stream>>>(trk, ws);
    attn_k<<<dim3(8, H_, NT_), 256, 0, stream>>>(q, kvk, kvv, gates, x, out, ws);
}

// Round 4
// 214.393 us; speedup vs baseline: 1.2645x; 1.2617x over previous
//
#include <hip/hip_runtime.h>

// Problem constants (B,H,T,D = 4,16,4096,64; N_TASKS=8, K_LEN=128)
#define B_   4
#define H_   16
#define T_   4096
#define D_   64
#define KL_  128
#define NT_  8
#define NTOK (B_ * T_)      // 16384 tokens
#define CAP  4096           // fixed bucket capacity (avg 2048, binomial max ~2300)

typedef __bf16 bf16;
typedef __attribute__((ext_vector_type(8))) __bf16 bf16x8;
typedef __attribute__((ext_vector_type(4))) __bf16 bf16x4;
typedef __attribute__((ext_vector_type(4))) float  floatx4;
typedef __attribute__((ext_vector_type(4))) unsigned int uint4v;

// ws layout (ints): [0..7] per-task counts; [8 ..] buckets, CAP per task.
__global__ void zero_counts_k(int* __restrict__ ws) {
    if (threadIdx.x < NT_) ws[threadIdx.x] = 0;
}

// One thread per token; wave-aggregated atomics (8 atomics/wave, not 64).
__global__ void scatter_tokens_k(const int* __restrict__ trk, int* __restrict__ ws) {
    int* counts = ws;
    int* bucket = ws + NT_;
    int idx  = blockIdx.x * blockDim.x + threadIdx.x;
    int lane = threadIdx.x & 63;
    int task = (idx < NTOK) ? trk[idx] : -1;
    unsigned long long mymask = 0ull;
    int myCnt = 0;
#pragma unroll
    for (int i = 0; i < NT_; i++) {
        unsigned long long m = __ballot(task == i);
        if (task == i) mymask = m;
        if (lane == i) myCnt = (int)__popcll(m);
    }
    int b0 = 0;
    if (lane < NT_) b0 = atomicAdd(&counts[lane], myCnt);
    int myBase = __shfl(b0, (task < 0) ? 0 : task);
    if (idx < NTOK) {
        int pos = myBase + (int)__popcll(mymask & ((1ull << lane) - 1ull));
        bucket[task * CAP + pos] = idx;   // token id = b*T + t
    }
}

static __device__ __forceinline__ unsigned pk_bf16(float a, float b) {
    unsigned short ua = __builtin_bit_cast(unsigned short, (bf16)a);
    unsigned short ub = __builtin_bit_cast(unsigned short, (bf16)b);
    return (unsigned)ua | ((unsigned)ub << 16);
}

// Swapped-S flash attention per (task, head, chunk).
// LDS: K [128][64] bf16 XOR-swizzled (16 KB) + V^T [64][128] bf16 XOR-swizzled (16 KB) = 32 KB
// -> 5 blocks/CU (20 waves/CU).
// REGISTER LESSON (rounds 1-2): any waves-per-EU hint (launch_bounds min or
// amdgpu_waves_per_eu) drove the allocator to a 64-VGPR target and spilled sc[8]
// (+260 MB scratch HBM traffic). Plain __launch_bounds__(256) let it pick 84 regs
// spill-free in round 0 — so: NO waves hints, and keep peak live regs < ~100 by
// loading x only after sc[] dies (post P-pack).
// S^T = mfma(K, Q): lane (c=lane&15, quad=lane>>4) holds, for token c, keys nt*16+quad*4+r.
// Softmax is lane-local + 2 shfl_xor. P->A-layout via in-register cross-quad shuffles (no LDS).
__global__ __launch_bounds__(256) void attn_k(
    const float* __restrict__ q,   const float* __restrict__ kvk,
    const float* __restrict__ kvv, const float* __restrict__ gates,
    const float* __restrict__ x,   float* __restrict__ out,
    const int* __restrict__ ws)
{
    __shared__ bf16 Kl[KL_ * D_];   // [k][d], 16B-unit swizzle: u ^= (k&7)
    __shared__ bf16 Vt[D_ * KL_];   // [d][k], 16B-unit swizzle: u ^= (d&7)

    const int task = blockIdx.z, h = blockIdx.y, chunk = blockIdx.x;
    const int cnt = ws[task];
    if (cnt == 0) return;
    const int* bucket = ws + NT_ + task * CAP;
    const float gate = gates[task];

    // ---- stage K and V^T (bf16, swizzled, no pad) ----
    {
        const size_t kvbase = (size_t)(task * H_ + h) * (KL_ * D_ / 4);
        const float4* kf = (const float4*)kvk + kvbase;
        const float4* vf = (const float4*)kvv + kvbase;
#pragma unroll
        for (int it = 0; it < 8; it++) {
            int ii = it * 256 + threadIdx.x;
            int k = ii >> 4, d4 = ii & 15;
            float4 a = kf[ii];
            bf16x4 w; w[0]=(bf16)a.x; w[1]=(bf16)a.y; w[2]=(bf16)a.z; w[3]=(bf16)a.w;
            // row k (64 elems = 8 units of 8 bf16); unit = d4>>1, half = d4&1
            *(bf16x4*)&Kl[(k << 6) + (((d4 >> 1) ^ (k & 7)) << 3) + ((d4 & 1) << 2)] = w;
            float4 v = vf[ii];
            int d0 = d4 << 2, ku = k >> 3, kl = k & 7;
            Vt[(d0+0)*128 + ((ku ^ ((d0+0)&7))<<3) + kl] = (bf16)v.x;
            Vt[(d0+1)*128 + ((ku ^ ((d0+1)&7))<<3) + kl] = (bf16)v.y;
            Vt[(d0+2)*128 + ((ku ^ ((d0+2)&7))<<3) + kl] = (bf16)v.z;
            Vt[(d0+3)*128 + ((ku ^ ((d0+3)&7))<<3) + kl] = (bf16)v.w;
        }
    }
    __syncthreads();

    const int lane = threadIdx.x & 63;
    const int wave = threadIdx.x >> 6;
    const int c = lane & 15, quad = lane >> 4;
    const int cswz = c & 7;
    // P-routing source lanes: dword half hsel pulls pk[..][t] from lane c+16*((2q+h)&3)
    const int src_h0 = c + 16 * (( 2 * quad     ) & 3);
    const int src_h1 = c + 16 * (( 2 * quad + 1 ) & 3);
    const bool hiSel = ((quad >> 1) & 1) != 0;   // pick pk[2kc+1] vs pk[2kc]

    // grid: 16 chunks x 4 waves = 64 tile slots, stride 64 (2048 blocks -> LDS-capped
    // occupancy 5 blocks/CU instead of the old 50% grid cap).
    for (int ts = chunk * 4 + wave; ts * 16 < cnt; ts += 64) {
        const int slotc = ts * 16 + c;
        const int tokc  = bucket[slotc < cnt ? slotc : cnt - 1];

        // ---- Q fragment (B-operand: n = token c, k-dim = quad*8+j) ----
        bf16x8 aq[2];
        {
            int bb = tokc >> 12, tt = tokc & (T_ - 1);
            const float4* qf = (const float4*)q + ((size_t)((bb * H_ + h) * T_ + tt) * (D_ / 4));
#pragma unroll
            for (int dc = 0; dc < 2; dc++) {
                float4 f0 = qf[dc * 8 + quad * 2];
                float4 f1 = qf[dc * 8 + quad * 2 + 1];
                aq[dc][0]=(bf16)f0.x; aq[dc][1]=(bf16)f0.y; aq[dc][2]=(bf16)f0.z; aq[dc][3]=(bf16)f0.w;
                aq[dc][4]=(bf16)f1.x; aq[dc][5]=(bf16)f1.y; aq[dc][6]=(bf16)f1.z; aq[dc][7]=(bf16)f1.w;
            }
        }

        // ---- S^T = K Q^T : 8 key-tiles x 2 d-chunks (operand-swapped MFMA) ----
        floatx4 sc[8];
#pragma unroll
        for (int nt = 0; nt < 8; nt++) { floatx4 z = {0.f,0.f,0.f,0.f}; sc[nt] = z; }
        __builtin_amdgcn_s_setprio(1);
#pragma unroll
        for (int dc = 0; dc < 2; dc++) {
#pragma unroll
            for (int nt = 0; nt < 8; nt++) {
                bf16x8 ak = *(const bf16x8*)&Kl[((nt * 16 + c) << 6) + (((4 * dc + quad) ^ cswz) << 3)];
                sc[nt] = __builtin_amdgcn_mfma_f32_16x16x32_bf16(ak, aq[dc], sc[nt], 0, 0, 0);
            }
        }
        __builtin_amdgcn_s_setprio(0);

        // ---- softmax: lane-local over 32 vals + reduce across quads (2 shuffles) ----
        float m = -1e30f;
#pragma unroll
        for (int nt = 0; nt < 8; nt++)
#pragma unroll
            for (int r = 0; r < 4; r++) m = fmaxf(m, sc[nt][r]);
        m = fmaxf(m, __shfl_xor(m, 16));
        m = fmaxf(m, __shfl_xor(m, 32));
        float sum = 0.f;
#pragma unroll
        for (int nt = 0; nt < 8; nt++)
#pragma unroll
            for (int r = 0; r < 4; r++) {
                // scale 1/sqrt(64)=0.125 folded into exp2: 0.125*log2(e)
                float p = exp2f((sc[nt][r] - m) * 0.18033688011112042f);
                sc[nt][r] = p;
                sum += p;
            }
        sum += __shfl_xor(sum, 16);
        sum += __shfl_xor(sum, 32);
        float ginv = gate / sum;

        // ---- pack P to bf16 pairs: pkv[nt][t] = (P[16nt+4q+2t], P[16nt+4q+2t+1]) ----
        unsigned pkv[8][2];
#pragma unroll
        for (int nt = 0; nt < 8; nt++) {
            pkv[nt][0] = pk_bf16(sc[nt][0], sc[nt][1]);
            pkv[nt][1] = pk_bf16(sc[nt][2], sc[nt][3]);
        }

        // ---- x prefetch (AFTER sc[] dies -> peak regs stay < budget; latency hides
        //      under the 16 PV MFMAs + routing shuffles) ----
        int base_r[4];
        float xr[4][4];
#pragma unroll
        for (int r = 0; r < 4; r++) {
            int tok = __shfl(tokc, quad * 4 + r);
            int b2 = tok >> 12, t2 = tok & (T_ - 1);
            base_r[r] = ((b2 * H_ + h) * T_ + t2) * D_;
            if (ts * 16 + quad * 4 + r < cnt) {
#pragma unroll
                for (int dt = 0; dt < 4; dt++) xr[r][dt] = x[base_r[r] + dt * 16 + c];
            }
        }

        // ---- O = P V : in-register P routing (keys kc*32+quad*8+j per lane) + 16 MFMA ----
        floatx4 acc[4];
#pragma unroll
        for (int dt = 0; dt < 4; dt++) { floatx4 z = {0.f,0.f,0.f,0.f}; acc[dt] = z; }
#pragma unroll
        for (int kc = 0; kc < 4; kc++) {
            unsigned e0 = pkv[2*kc][0],   e1 = pkv[2*kc][1];
            unsigned o0 = pkv[2*kc+1][0], o1 = pkv[2*kc+1][1];
            unsigned a0e = __shfl(e0, src_h0), a0o = __shfl(o0, src_h0);
            unsigned a1e = __shfl(e1, src_h0), a1o = __shfl(o1, src_h0);
            unsigned a2e = __shfl(e0, src_h1), a2o = __shfl(o0, src_h1);
            unsigned a3e = __shfl(e1, src_h1), a3o = __shfl(o1, src_h1);
            uint4v uw;
            uw[0] = hiSel ? a0o : a0e;
            uw[1] = hiSel ? a1o : a1e;
            uw[2] = hiSel ? a2o : a2e;
            uw[3] = hiSel ? a3o : a3e;
            bf16x8 ap = __builtin_bit_cast(bf16x8, uw);
            __builtin_amdgcn_s_setprio(1);
#pragma unroll
            for (int dt = 0; dt < 4; dt++) {
                bf16x8 bv = *(const bf16x8*)&Vt[((dt * 16 + c) << 7) + (((4 * kc + quad) ^ cswz) << 3)];
                acc[dt] = __builtin_amdgcn_mfma_f32_16x16x32_bf16(ap, bv, acc[dt], 0, 0, 0);
            }
            __builtin_amdgcn_s_setprio(0);
        }

        // ---- epilogue: normalize, gate, residual add, store ----
#pragma unroll
        for (int r = 0; r < 4; r++) {
            int slot = ts * 16 + quad * 4 + r;
            float scale = __shfl(ginv, quad * 4 + r);
            if (slot < cnt) {
#pragma unroll
                for (int dt = 0; dt < 4; dt++) {
                    int off = base_r[r] + dt * 16 + c;
                    out[off] = xr[r][dt] + acc[dt][r] * scale;
                }
            }
        }
    }
}

extern "C" void kernel_launch(void* const* d_in, const int* in_sizes, int n_in,
                              void* d_out, int out_size, void* d_ws, size_t ws_size,
                              hipStream_t stream) {
    const float* x     = (const float*)d_in[0];
    const float* q     = (const float*)d_in[1];
    const float* kvk   = (const float*)d_in[2];
    const float* kvv   = (const float*)d_in[3];
    const float* gates = (const float*)d_in[4];
    const int*   trk   = (const int*)d_in[5];
    float* out = (float*)d_out;
    int* ws = (int*)d_ws;

    zero_counts_k<<<1, 64, 0, stream>>>(ws);
    scatter_tokens_k<<<NTOK / 256, 256, 0, stream>>>(trk, ws);
    attn_k<<<dim3(16, H_, NT_), 256, 0, stream>>>(q, kvk, kvv, gates, x, out, ws);
}

// Round 5
// 206.618 us; speedup vs baseline: 1.3121x; 1.0376x over previous
//
#include <hip/hip_runtime.h>

// Problem constants (B,H,T,D = 4,16,4096,64; N_TASKS=8, K_LEN=128)
#define B_   4
#define H_   16
#define T_   4096
#define D_   64
#define KL_  128
#define NT_  8
#define NTOK (B_ * T_)      // 16384 tokens
#define CAP  4096           // fixed bucket capacity (avg 2048, binomial max ~2300)

typedef __bf16 bf16;
typedef __attribute__((ext_vector_type(8))) __bf16 bf16x8;
typedef __attribute__((ext_vector_type(4))) __bf16 bf16x4;
typedef __attribute__((ext_vector_type(4))) float  floatx4;
typedef __attribute__((ext_vector_type(4))) unsigned int uint4v;

// ws layout (ints): [0..7] per-task counts; [8 ..] buckets, CAP per task.
__global__ void zero_counts_k(int* __restrict__ ws) {
    if (threadIdx.x < NT_) ws[threadIdx.x] = 0;
}

// One thread per token; wave-aggregated atomics (8 atomics/wave, not 64).
__global__ void scatter_tokens_k(const int* __restrict__ trk, int* __restrict__ ws) {
    int* counts = ws;
    int* bucket = ws + NT_;
    int idx  = blockIdx.x * blockDim.x + threadIdx.x;
    int lane = threadIdx.x & 63;
    int task = (idx < NTOK) ? trk[idx] : -1;
    unsigned long long mymask = 0ull;
    int myCnt = 0;
#pragma unroll
    for (int i = 0; i < NT_; i++) {
        unsigned long long m = __ballot(task == i);
        if (task == i) mymask = m;
        if (lane == i) myCnt = (int)__popcll(m);
    }
    int b0 = 0;
    if (lane < NT_) b0 = atomicAdd(&counts[lane], myCnt);
    int myBase = __shfl(b0, (task < 0) ? 0 : task);
    if (idx < NTOK) {
        int pos = myBase + (int)__popcll(mymask & ((1ull << lane) - 1ull));
        bucket[task * CAP + pos] = idx;   // token id = b*T + t
    }
}

static __device__ __forceinline__ unsigned pk_bf16(float a, float b) {
    unsigned short ua = __builtin_bit_cast(unsigned short, (bf16)a);
    unsigned short ub = __builtin_bit_cast(unsigned short, (bf16)b);
    return (unsigned)ua | ((unsigned)ub << 16);
}

// Swapped-S flash attention per (task, head, chunk), 2-deep software pipeline.
// LDS: K [128][64] bf16 XOR-swizzled (16 KB) + V^T [64][128] bf16 XOR-swizzled (16 KB) = 32 KB.
// REGISTER LESSON (rounds 1-2, PROTECTED): any waves-per-EU hint (launch_bounds min or
// amdgpu_waves_per_eu) drove the allocator to a 64-VGPR target and spilled sc[8]
// (+260 MB scratch HBM traffic). Plain __launch_bounds__(256) -> 116 VGPR spill-free
// (round 4). Keep peak live regs < ~110: x loads only after sc[] dies (post P-pack).
// PIPELINE (round 5): each iteration prefetches the NEXT slot's bucket entry (issued
// before QK; L2 latency hides under QK+softmax) and NEXT Q fragment (issued after
// P-pack; HBM latency hides under x-load+routing+PV+epilogue+next QK). 1024 blocks
// -> 4 iters/wave so 3/4 of iterations run with warm prefetch.
// S^T = mfma(K, Q): lane (c=lane&15, quad=lane>>4) holds, for token c, keys nt*16+quad*4+r.
// Softmax is lane-local + 2 shfl_xor. P->A-layout via in-register cross-quad shuffles (no LDS).
__global__ __launch_bounds__(256) void attn_k(
    const float* __restrict__ q,   const float* __restrict__ kvk,
    const float* __restrict__ kvv, const float* __restrict__ gates,
    const float* __restrict__ x,   float* __restrict__ out,
    const int* __restrict__ ws)
{
    __shared__ bf16 Kl[KL_ * D_];   // [k][d], 16B-unit swizzle: u ^= (k&7)
    __shared__ bf16 Vt[D_ * KL_];   // [d][k], 16B-unit swizzle: u ^= (d&7)

    const int task = blockIdx.z, h = blockIdx.y, chunk = blockIdx.x;
    const int cnt = ws[task];
    if (cnt == 0) return;
    const int* bucket = ws + NT_ + task * CAP;
    const float gate = gates[task];

    // ---- stage K and V^T (bf16, swizzled, no pad) ----
    {
        const size_t kvbase = (size_t)(task * H_ + h) * (KL_ * D_ / 4);
        const float4* kf = (const float4*)kvk + kvbase;
        const float4* vf = (const float4*)kvv + kvbase;
#pragma unroll
        for (int it = 0; it < 8; it++) {
            int ii = it * 256 + threadIdx.x;
            int k = ii >> 4, d4 = ii & 15;
            float4 a = kf[ii];
            bf16x4 w; w[0]=(bf16)a.x; w[1]=(bf16)a.y; w[2]=(bf16)a.z; w[3]=(bf16)a.w;
            // row k (64 elems = 8 units of 8 bf16); unit = d4>>1, half = d4&1
            *(bf16x4*)&Kl[(k << 6) + (((d4 >> 1) ^ (k & 7)) << 3) + ((d4 & 1) << 2)] = w;
            float4 v = vf[ii];
            int d0 = d4 << 2, ku = k >> 3, kl = k & 7;
            Vt[(d0+0)*128 + ((ku ^ ((d0+0)&7))<<3) + kl] = (bf16)v.x;
            Vt[(d0+1)*128 + ((ku ^ ((d0+1)&7))<<3) + kl] = (bf16)v.y;
            Vt[(d0+2)*128 + ((ku ^ ((d0+2)&7))<<3) + kl] = (bf16)v.z;
            Vt[(d0+3)*128 + ((ku ^ ((d0+3)&7))<<3) + kl] = (bf16)v.w;
        }
    }
    __syncthreads();

    const int lane = threadIdx.x & 63;
    const int wave = threadIdx.x >> 6;
    const int c = lane & 15, quad = lane >> 4;
    const int cswz = c & 7;
    // P-routing source lanes: dword half hsel pulls pk[..][t] from lane c+16*((2q+h)&3)
    const int src_h0 = c + 16 * (( 2 * quad     ) & 3);
    const int src_h1 = c + 16 * (( 2 * quad + 1 ) & 3);
    const bool hiSel = ((quad >> 1) & 1) != 0;   // pick pk[2kc+1] vs pk[2kc]

    const float4* qbase = (const float4*)q;

    // ---- pipeline prologue: bucket token + Q fragment for the first slot ----
    int ts0 = chunk * 4 + wave;
    int tokc;
    bf16x8 aq[2];
    {
        int slotc = ts0 * 16 + c;
        tokc = bucket[slotc < cnt ? slotc : cnt - 1];
        int bb = tokc >> 12, tt = tokc & (T_ - 1);
        const float4* qf = qbase + ((size_t)((bb * H_ + h) * T_ + tt) * (D_ / 4));
#pragma unroll
        for (int dc = 0; dc < 2; dc++) {
            float4 f0 = qf[dc * 8 + quad * 2];
            float4 f1 = qf[dc * 8 + quad * 2 + 1];
            aq[dc][0]=(bf16)f0.x; aq[dc][1]=(bf16)f0.y; aq[dc][2]=(bf16)f0.z; aq[dc][3]=(bf16)f0.w;
            aq[dc][4]=(bf16)f1.x; aq[dc][5]=(bf16)f1.y; aq[dc][6]=(bf16)f1.z; aq[dc][7]=(bf16)f1.w;
        }
    }

    // grid: 8 chunks x 4 waves = 32 tile slots, stride 32 -> ~4 iters/wave.
    for (int ts = ts0; ts * 16 < cnt; ts += 32) {
        // ---- issue NEXT slot's bucket load (L2; hides under QK + softmax) ----
        int slotn = (ts + 32) * 16 + c;
        const int tokn = bucket[slotn < cnt ? slotn : cnt - 1];

        // ---- S^T = K Q^T : 8 key-tiles x 2 d-chunks (operand-swapped MFMA) ----
        floatx4 sc[8];
#pragma unroll
        for (int nt = 0; nt < 8; nt++) { floatx4 z = {0.f,0.f,0.f,0.f}; sc[nt] = z; }
        __builtin_amdgcn_s_setprio(1);
#pragma unroll
        for (int dc = 0; dc < 2; dc++) {
#pragma unroll
            for (int nt = 0; nt < 8; nt++) {
                bf16x8 ak = *(const bf16x8*)&Kl[((nt * 16 + c) << 6) + (((4 * dc + quad) ^ cswz) << 3)];
                sc[nt] = __builtin_amdgcn_mfma_f32_16x16x32_bf16(ak, aq[dc], sc[nt], 0, 0, 0);
            }
        }
        __builtin_amdgcn_s_setprio(0);

        // ---- softmax: lane-local over 32 vals + reduce across quads (2 shuffles) ----
        float m = -1e30f;
#pragma unroll
        for (int nt = 0; nt < 8; nt++)
#pragma unroll
            for (int r = 0; r < 4; r++) m = fmaxf(m, sc[nt][r]);
        m = fmaxf(m, __shfl_xor(m, 16));
        m = fmaxf(m, __shfl_xor(m, 32));
        float sum = 0.f;
#pragma unroll
        for (int nt = 0; nt < 8; nt++)
#pragma unroll
            for (int r = 0; r < 4; r++) {
                // scale 1/sqrt(64)=0.125 folded into exp2: 0.125*log2(e)
                float p = exp2f((sc[nt][r] - m) * 0.18033688011112042f);
                sc[nt][r] = p;
                sum += p;
            }
        sum += __shfl_xor(sum, 16);
        sum += __shfl_xor(sum, 32);
        float ginv = gate / sum;

        // ---- pack P to bf16 pairs: pkv[nt][t] = (P[16nt+4q+2t], P[16nt+4q+2t+1]) ----
        unsigned pkv[8][2];
#pragma unroll
        for (int nt = 0; nt < 8; nt++) {
            pkv[nt][0] = pk_bf16(sc[nt][0], sc[nt][1]);
            pkv[nt][1] = pk_bf16(sc[nt][2], sc[nt][3]);
        }

        // ---- issue NEXT Q fragment loads (HBM; hides under x+routing+PV+epilogue) ----
        bf16x8 aqn[2];
        {
            int bb = tokn >> 12, tt = tokn & (T_ - 1);
            const float4* qf = qbase + ((size_t)((bb * H_ + h) * T_ + tt) * (D_ / 4));
#pragma unroll
            for (int dc = 0; dc < 2; dc++) {
                float4 f0 = qf[dc * 8 + quad * 2];
                float4 f1 = qf[dc * 8 + quad * 2 + 1];
                aqn[dc][0]=(bf16)f0.x; aqn[dc][1]=(bf16)f0.y; aqn[dc][2]=(bf16)f0.z; aqn[dc][3]=(bf16)f0.w;
                aqn[dc][4]=(bf16)f1.x; aqn[dc][5]=(bf16)f1.y; aqn[dc][6]=(bf16)f1.z; aqn[dc][7]=(bf16)f1.w;
            }
        }

        // ---- x load for CURRENT tokens (after sc[] dies; hides under routing+PV) ----
        int base_r[4];
        float xr[4][4];
#pragma unroll
        for (int r = 0; r < 4; r++) {
            int tok = __shfl(tokc, quad * 4 + r);
            int b2 = tok >> 12, t2 = tok & (T_ - 1);
            base_r[r] = ((b2 * H_ + h) * T_ + t2) * D_;
            if (ts * 16 + quad * 4 + r < cnt) {
#pragma unroll
                for (int dt = 0; dt < 4; dt++) xr[r][dt] = x[base_r[r] + dt * 16 + c];
            }
        }

        // ---- O = P V : in-register P routing (keys kc*32+quad*8+j per lane) + 16 MFMA ----
        floatx4 acc[4];
#pragma unroll
        for (int dt = 0; dt < 4; dt++) { floatx4 z = {0.f,0.f,0.f,0.f}; acc[dt] = z; }
#pragma unroll
        for (int kc = 0; kc < 4; kc++) {
            unsigned e0 = pkv[2*kc][0],   e1 = pkv[2*kc][1];
            unsigned o0 = pkv[2*kc+1][0], o1 = pkv[2*kc+1][1];
            unsigned a0e = __shfl(e0, src_h0), a0o = __shfl(o0, src_h0);
            unsigned a1e = __shfl(e1, src_h0), a1o = __shfl(o1, src_h0);
            unsigned a2e = __shfl(e0, src_h1), a2o = __shfl(o0, src_h1);
            unsigned a3e = __shfl(e1, src_h1), a3o = __shfl(o1, src_h1);
            uint4v uw;
            uw[0] = hiSel ? a0o : a0e;
            uw[1] = hiSel ? a1o : a1e;
            uw[2] = hiSel ? a2o : a2e;
            uw[3] = hiSel ? a3o : a3e;
            bf16x8 ap = __builtin_bit_cast(bf16x8, uw);
            __builtin_amdgcn_s_setprio(1);
#pragma unroll
            for (int dt = 0; dt < 4; dt++) {
                bf16x8 bv = *(const bf16x8*)&Vt[((dt * 16 + c) << 7) + (((4 * kc + quad) ^ cswz) << 3)];
                acc[dt] = __builtin_amdgcn_mfma_f32_16x16x32_bf16(ap, bv, acc[dt], 0, 0, 0);
            }
            __builtin_amdgcn_s_setprio(0);
        }

        // ---- epilogue: normalize, gate, residual add, store ----
#pragma unroll
        for (int r = 0; r < 4; r++) {
            int slot = ts * 16 + quad * 4 + r;
            float scale = __shfl(ginv, quad * 4 + r);
            if (slot < cnt) {
#pragma unroll
                for (int dt = 0; dt < 4; dt++) {
                    int off = base_r[r] + dt * 16 + c;
                    out[off] = xr[r][dt] + acc[dt][r] * scale;
                }
            }
        }

        // ---- rotate pipeline state ----
        tokc = tokn;
        aq[0] = aqn[0];
        aq[1] = aqn[1];
    }
}

extern "C" void kernel_launch(void* const* d_in, const int* in_sizes, int n_in,
                              void* d_out, int out_size, void* d_ws, size_t ws_size,
                              hipStream_t stream) {
    const float* x     = (const float*)d_in[0];
    const float* q     = (const float*)d_in[1];
    const float* kvk   = (const float*)d_in[2];
    const float* kvv   = (const float*)d_in[3];
    const float* gates = (const float*)d_in[4];
    const int*   trk   = (const int*)d_in[5];
    float* out = (float*)d_out;
    int* ws = (int*)d_ws;

    zero_counts_k<<<1, 64, 0, stream>>>(ws);
    scatter_tokens_k<<<NTOK / 256, 256, 0, stream>>>(trk, ws);
    attn_k<<<dim3(8, H_, NT_), 256, 0, stream>>>(q, kvk, kvv, gates, x, out, ws);
}

// Round 6
// 206.230 us; speedup vs baseline: 1.3145x; 1.0019x over previous
//
#include <hip/hip_runtime.h>

// Problem constants (B,H,T,D = 4,16,4096,64; N_TASKS=8, K_LEN=128)
#define B_   4
#define H_   16
#define T_   4096
#define D_   64
#define KL_  128
#define NT_  8
#define NTOK (B_ * T_)      // 16384 tokens
#define CAP  4096           // fixed bucket capacity (avg 2048, binomial max ~2300)

typedef __bf16 bf16;
typedef __attribute__((ext_vector_type(8))) __bf16 bf16x8;
typedef __attribute__((ext_vector_type(4))) __bf16 bf16x4;
typedef __attribute__((ext_vector_type(4))) float  floatx4;
typedef __attribute__((ext_vector_type(4))) unsigned int uint4v;

// ROUND-6 HYPOTHESIS: d_ws may be host-visible/PCIe-resident memory (explains the
// constant ~126 us gap between total and attn_k, and attn's 48k-cycle/iter stalls).
// All bucket state lives in a static __device__ global: guaranteed device HBM,
// no hipMalloc (graph-safe). d_ws is deliberately unused.
__device__ int g_ws[NT_ + NT_ * CAP];

__global__ void zero_counts_k() {
    if (threadIdx.x < NT_) g_ws[threadIdx.x] = 0;
}

// One thread per token; wave-aggregated atomics (8 atomics/wave, not 64).
__global__ void scatter_tokens_k(const int* __restrict__ trk) {
    int* counts = g_ws;
    int* bucket = g_ws + NT_;
    int idx  = blockIdx.x * blockDim.x + threadIdx.x;
    int lane = threadIdx.x & 63;
    int task = (idx < NTOK) ? trk[idx] : -1;
    unsigned long long mymask = 0ull;
    int myCnt = 0;
#pragma unroll
    for (int i = 0; i < NT_; i++) {
        unsigned long long m = __ballot(task == i);
        if (task == i) mymask = m;
        if (lane == i) myCnt = (int)__popcll(m);
    }
    int b0 = 0;
    if (lane < NT_) b0 = atomicAdd(&counts[lane], myCnt);
    int myBase = __shfl(b0, (task < 0) ? 0 : task);
    if (idx < NTOK) {
        int pos = myBase + (int)__popcll(mymask & ((1ull << lane) - 1ull));
        bucket[task * CAP + pos] = idx;   // token id = b*T + t
    }
}

static __device__ __forceinline__ unsigned pk_bf16(float a, float b) {
    unsigned short ua = __builtin_bit_cast(unsigned short, (bf16)a);
    unsigned short ub = __builtin_bit_cast(unsigned short, (bf16)b);
    return (unsigned)ua | ((unsigned)ub << 16);
}

// Swapped-S flash attention per (task, head, chunk), 2-deep software pipeline.
// LDS: K [128][64] bf16 XOR-swizzled (16 KB) + V^T [64][128] bf16 XOR-swizzled (16 KB) = 32 KB.
// REGISTER LESSON (rounds 1-2, PROTECTED): any waves-per-EU hint (launch_bounds min or
// amdgpu_waves_per_eu) drove the allocator to a 64-VGPR target and spilled sc[8]
// (+260 MB scratch HBM traffic). Plain __launch_bounds__(256) -> 116-124 VGPR spill-free.
// Keep peak live regs < ~110: x loads only after sc[] dies (post P-pack).
// PIPELINE (round 5): prefetch NEXT slot's bucket entry (top of loop) and NEXT Q
// fragment (after P-pack). Round 6: prologue bucket+Q loads issued BEFORE staging
// so their HBM latency hides under the K/V staging phase.
// S^T = mfma(K, Q): lane (c=lane&15, quad=lane>>4) holds, for token c, keys nt*16+quad*4+r.
// Softmax is lane-local + 2 shfl_xor. P->A-layout via in-register cross-quad shuffles (no LDS).
__global__ __launch_bounds__(256) void attn_k(
    const float* __restrict__ q,   const float* __restrict__ kvk,
    const float* __restrict__ kvv, const float* __restrict__ gates,
    const float* __restrict__ x,   float* __restrict__ out)
{
    __shared__ bf16 Kl[KL_ * D_];   // [k][d], 16B-unit swizzle: u ^= (k&7)
    __shared__ bf16 Vt[D_ * KL_];   // [d][k], 16B-unit swizzle: u ^= (d&7)

    const int task = blockIdx.z, h = blockIdx.y, chunk = blockIdx.x;
    const int cnt = g_ws[task];
    if (cnt == 0) return;
    const int* bucket = g_ws + NT_ + task * CAP;
    const float gate = gates[task];

    const int lane = threadIdx.x & 63;
    const int wave = threadIdx.x >> 6;
    const int c = lane & 15, quad = lane >> 4;
    const int cswz = c & 7;
    const float4* qbase = (const float4*)q;

    // ---- pipeline prologue: bucket token + Q fragment for the first slot.
    //      Issued BEFORE staging so HBM latency hides under the staging loop. ----
    int ts0 = chunk * 4 + wave;
    int tokc;
    bf16x8 aq[2];
    {
        int slotc = ts0 * 16 + c;
        tokc = bucket[slotc < cnt ? slotc : cnt - 1];
        int bb = tokc >> 12, tt = tokc & (T_ - 1);
        const float4* qf = qbase + ((size_t)((bb * H_ + h) * T_ + tt) * (D_ / 4));
#pragma unroll
        for (int dc = 0; dc < 2; dc++) {
            float4 f0 = qf[dc * 8 + quad * 2];
            float4 f1 = qf[dc * 8 + quad * 2 + 1];
            aq[dc][0]=(bf16)f0.x; aq[dc][1]=(bf16)f0.y; aq[dc][2]=(bf16)f0.z; aq[dc][3]=(bf16)f0.w;
            aq[dc][4]=(bf16)f1.x; aq[dc][5]=(bf16)f1.y; aq[dc][6]=(bf16)f1.z; aq[dc][7]=(bf16)f1.w;
        }
    }

    // ---- stage K and V^T (bf16, swizzled, no pad) ----
    {
        const size_t kvbase = (size_t)(task * H_ + h) * (KL_ * D_ / 4);
        const float4* kf = (const float4*)kvk + kvbase;
        const float4* vf = (const float4*)kvv + kvbase;
#pragma unroll
        for (int it = 0; it < 8; it++) {
            int ii = it * 256 + threadIdx.x;
            int k = ii >> 4, d4 = ii & 15;
            float4 a = kf[ii];
            bf16x4 w; w[0]=(bf16)a.x; w[1]=(bf16)a.y; w[2]=(bf16)a.z; w[3]=(bf16)a.w;
            // row k (64 elems = 8 units of 8 bf16); unit = d4>>1, half = d4&1
            *(bf16x4*)&Kl[(k << 6) + (((d4 >> 1) ^ (k & 7)) << 3) + ((d4 & 1) << 2)] = w;
            float4 v = vf[ii];
            int d0 = d4 << 2, ku = k >> 3, kl = k & 7;
            Vt[(d0+0)*128 + ((ku ^ ((d0+0)&7))<<3) + kl] = (bf16)v.x;
            Vt[(d0+1)*128 + ((ku ^ ((d0+1)&7))<<3) + kl] = (bf16)v.y;
            Vt[(d0+2)*128 + ((ku ^ ((d0+2)&7))<<3) + kl] = (bf16)v.z;
            Vt[(d0+3)*128 + ((ku ^ ((d0+3)&7))<<3) + kl] = (bf16)v.w;
        }
    }
    __syncthreads();

    // P-routing source lanes: dword half hsel pulls pk[..][t] from lane c+16*((2q+h)&3)
    const int src_h0 = c + 16 * (( 2 * quad     ) & 3);
    const int src_h1 = c + 16 * (( 2 * quad + 1 ) & 3);
    const bool hiSel = ((quad >> 1) & 1) != 0;   // pick pk[2kc+1] vs pk[2kc]

    // grid: 8 chunks x 4 waves = 32 tile slots, stride 32 -> ~4 iters/wave.
    for (int ts = ts0; ts * 16 < cnt; ts += 32) {
        // ---- issue NEXT slot's bucket load (hides under QK + softmax) ----
        int slotn = (ts + 32) * 16 + c;
        const int tokn = bucket[slotn < cnt ? slotn : cnt - 1];

        // ---- S^T = K Q^T : 8 key-tiles x 2 d-chunks (operand-swapped MFMA) ----
        floatx4 sc[8];
#pragma unroll
        for (int nt = 0; nt < 8; nt++) { floatx4 z = {0.f,0.f,0.f,0.f}; sc[nt] = z; }
        __builtin_amdgcn_s_setprio(1);
#pragma unroll
        for (int dc = 0; dc < 2; dc++) {
#pragma unroll
            for (int nt = 0; nt < 8; nt++) {
                bf16x8 ak = *(const bf16x8*)&Kl[((nt * 16 + c) << 6) + (((4 * dc + quad) ^ cswz) << 3)];
                sc[nt] = __builtin_amdgcn_mfma_f32_16x16x32_bf16(ak, aq[dc], sc[nt], 0, 0, 0);
            }
        }
        __builtin_amdgcn_s_setprio(0);

        // ---- softmax: lane-local over 32 vals + reduce across quads (2 shuffles) ----
        float m = -1e30f;
#pragma unroll
        for (int nt = 0; nt < 8; nt++)
#pragma unroll
            for (int r = 0; r < 4; r++) m = fmaxf(m, sc[nt][r]);
        m = fmaxf(m, __shfl_xor(m, 16));
        m = fmaxf(m, __shfl_xor(m, 32));
        float sum = 0.f;
#pragma unroll
        for (int nt = 0; nt < 8; nt++)
#pragma unroll
            for (int r = 0; r < 4; r++) {
                // scale 1/sqrt(64)=0.125 folded into exp2: 0.125*log2(e)
                float p = exp2f((sc[nt][r] - m) * 0.18033688011112042f);
                sc[nt][r] = p;
                sum += p;
            }
        sum += __shfl_xor(sum, 16);
        sum += __shfl_xor(sum, 32);
        float ginv = gate / sum;

        // ---- pack P to bf16 pairs: pkv[nt][t] = (P[16nt+4q+2t], P[16nt+4q+2t+1]) ----
        unsigned pkv[8][2];
#pragma unroll
        for (int nt = 0; nt < 8; nt++) {
            pkv[nt][0] = pk_bf16(sc[nt][0], sc[nt][1]);
            pkv[nt][1] = pk_bf16(sc[nt][2], sc[nt][3]);
        }

        // ---- issue NEXT Q fragment loads (HBM; hides under x+routing+PV+epilogue) ----
        bf16x8 aqn[2];
        {
            int bb = tokn >> 12, tt = tokn & (T_ - 1);
            const float4* qf = qbase + ((size_t)((bb * H_ + h) * T_ + tt) * (D_ / 4));
#pragma unroll
            for (int dc = 0; dc < 2; dc++) {
                float4 f0 = qf[dc * 8 + quad * 2];
                float4 f1 = qf[dc * 8 + quad * 2 + 1];
                aqn[dc][0]=(bf16)f0.x; aqn[dc][1]=(bf16)f0.y; aqn[dc][2]=(bf16)f0.z; aqn[dc][3]=(bf16)f0.w;
                aqn[dc][4]=(bf16)f1.x; aqn[dc][5]=(bf16)f1.y; aqn[dc][6]=(bf16)f1.z; aqn[dc][7]=(bf16)f1.w;
            }
        }

        // ---- x load for CURRENT tokens (after sc[] dies; hides under routing+PV) ----
        int base_r[4];
        float xr[4][4];
#pragma unroll
        for (int r = 0; r < 4; r++) {
            int tok = __shfl(tokc, quad * 4 + r);
            int b2 = tok >> 12, t2 = tok & (T_ - 1);
            base_r[r] = ((b2 * H_ + h) * T_ + t2) * D_;
            if (ts * 16 + quad * 4 + r < cnt) {
#pragma unroll
                for (int dt = 0; dt < 4; dt++) xr[r][dt] = x[base_r[r] + dt * 16 + c];
            }
        }

        // ---- O = P V : in-register P routing (keys kc*32+quad*8+j per lane) + 16 MFMA ----
        floatx4 acc[4];
#pragma unroll
        for (int dt = 0; dt < 4; dt++) { floatx4 z = {0.f,0.f,0.f,0.f}; acc[dt] = z; }
#pragma unroll
        for (int kc = 0; kc < 4; kc++) {
            unsigned e0 = pkv[2*kc][0],   e1 = pkv[2*kc][1];
            unsigned o0 = pkv[2*kc+1][0], o1 = pkv[2*kc+1][1];
            unsigned a0e = __shfl(e0, src_h0), a0o = __shfl(o0, src_h0);
            unsigned a1e = __shfl(e1, src_h0), a1o = __shfl(o1, src_h0);
            unsigned a2e = __shfl(e0, src_h1), a2o = __shfl(o0, src_h1);
            unsigned a3e = __shfl(e1, src_h1), a3o = __shfl(o1, src_h1);
            uint4v uw;
            uw[0] = hiSel ? a0o : a0e;
            uw[1] = hiSel ? a1o : a1e;
            uw[2] = hiSel ? a2o : a2e;
            uw[3] = hiSel ? a3o : a3e;
            bf16x8 ap = __builtin_bit_cast(bf16x8, uw);
            __builtin_amdgcn_s_setprio(1);
#pragma unroll
            for (int dt = 0; dt < 4; dt++) {
                bf16x8 bv = *(const bf16x8*)&Vt[((dt * 16 + c) << 7) + (((4 * kc + quad) ^ cswz) << 3)];
                acc[dt] = __builtin_amdgcn_mfma_f32_16x16x32_bf16(ap, bv, acc[dt], 0, 0, 0);
            }
            __builtin_amdgcn_s_setprio(0);
        }

        // ---- epilogue: normalize, gate, residual add, store ----
#pragma unroll
        for (int r = 0; r < 4; r++) {
            int slot = ts * 16 + quad * 4 + r;
            float scale = __shfl(ginv, quad * 4 + r);
            if (slot < cnt) {
#pragma unroll
                for (int dt = 0; dt < 4; dt++) {
                    int off = base_r[r] + dt * 16 + c;
                    out[off] = xr[r][dt] + acc[dt][r] * scale;
                }
            }
        }

        // ---- rotate pipeline state ----
        tokc = tokn;
        aq[0] = aqn[0];
        aq[1] = aqn[1];
    }
}

extern "C" void kernel_launch(void* const* d_in, const int* in_sizes, int n_in,
                              void* d_out, int out_size, void* d_ws, size_t ws_size,
                              hipStream_t stream) {
    const float* x     = (const float*)d_in[0];
    const float* q     = (const float*)d_in[1];
    const float* kvk   = (const float*)d_in[2];
    const float* kvv   = (const float*)d_in[3];
    const float* gates = (const float*)d_in[4];
    const int*   trk   = (const int*)d_in[5];
    float* out = (float*)d_out;
    (void)d_ws; (void)ws_size;

    zero_counts_k<<<1, 64, 0, stream>>>();
    scatter_tokens_k<<<NTOK / 256, 256, 0, stream>>>(trk);
    attn_k<<<dim3(8, H_, NT_), 256, 0, stream>>>(q, kvk, kvv, gates, x, out);
}